// Round 12
// baseline (1708.687 us; speedup 1.0000x reference)
//
#include <hip/hip_runtime.h>
#include <hip/hip_cooperative_groups.h>

namespace cg = cooperative_groups;

// LSTM S=512,B=128,IN=256,H=512 — persistent kernel, 256 blocks x 512 thr =
// 8 rowgroups x 32 colgroups(16 hidden cols), 8 waves = (4 gates) x (2 K-halves).
// Round 12 = round 8's PROVEN tagged-LLC-ring protocol + 2 waves/SIMD via
// K-split (ILP doubling), v_perm unpack, cvt_pk bf16 packing, lean tag check.

#define SQ   512
#define BB   128
#define IN_  256
#define HH   512
#define RG   8
#define CGN  32
#define RINGHALF (BB * HH)     // dwords
#define RING_OFF 1024          // dwords (4 KB head, unused)

typedef float    f32x4 __attribute__((ext_vector_type(4)));
typedef short    s16x8 __attribute__((ext_vector_type(8)));
typedef unsigned u32x4 __attribute__((ext_vector_type(4)));

struct P {
  const float *x, *h0, *c0;
  const float *W[4], *bW[4], *U[4], *bU[4];   // gate order f,i,o,g
  float* out;        // [SQ][BB][HH] h_seq, then [BB][HH] h, then [BB][HH] c
  unsigned* ring;    // [2][BB][HH] tagged bf16 h (lo16=payload, hi16=tag)
  int mode;          // 0 = ring protocol, 2 = gridsync fallback (no ws)
};

__device__ __forceinline__ unsigned f2b(float f) {
  unsigned u = __float_as_uint(f);
  return (u + 0x7FFFu + ((u >> 16) & 1u)) >> 16;   // RNE f32->bf16
}
__device__ __forceinline__ float sigm(float x) { return 1.f / (1.f + __expf(-x)); }
__device__ __forceinline__ float tanh_(float x) {
  float e = __expf(-2.f * fabsf(x));
  float t = (1.f - e) / (1.f + e);
  return copysignf(t, x);
}
// pack 2 f32 -> 2 bf16 in one dword (RNE), hardware cvt
__device__ __forceinline__ unsigned cvtpk(float lo, float hi) {
  unsigned r;
  asm("v_cvt_pk_bf16_f32 %0, %1, %2" : "=v"(r) : "v"(lo), "v"(hi));
  return r;
}
__device__ __forceinline__ u32x4 pack8(f32x4 a, f32x4 b) {
  u32x4 d;
  d.x = cvtpk(a.x, a.y); d.y = cvtpk(a.z, a.w);
  d.z = cvtpk(b.x, b.y); d.w = cvtpk(b.z, b.w);
  return d;
}
// merge lo16 of d0 (->bytes 0,1) and lo16 of d1 (->bytes 2,3)
__device__ __forceinline__ unsigned mergelo(unsigned d0, unsigned d1) {
  return __builtin_amdgcn_perm(d1, d0, 0x05040100u);
}

// 4x dwordx4 at base + {0,512,1024,1536}B, ONE waitcnt, LLC-coherent.
#define LOAD4S_LLC(c0_,c1_,c2_,c3_,ptr_)                                     \
  asm volatile(                                                              \
    "global_load_dwordx4 %0, %4, off sc0 sc1\n\t"                            \
    "global_load_dwordx4 %1, %4, off offset:512 sc0 sc1\n\t"                 \
    "global_load_dwordx4 %2, %4, off offset:1024 sc0 sc1\n\t"                \
    "global_load_dwordx4 %3, %4, off offset:1536 sc0 sc1\n\t"                \
    "s_waitcnt vmcnt(0)"                                                     \
    : "=&v"(c0_), "=&v"(c1_), "=&v"(c2_), "=&v"(c3_)                         \
    : "v"(ptr_) : "memory")

__global__ void __launch_bounds__(512, 1) lstm_all(P p) {
  __shared__ unsigned short Hs[16][512];      // h bf16, rows 1024B, XOR swz
  __shared__ unsigned short Xs[2][16][256];   // x bf16 dbuf, rows 512B, XOR swz
  __shared__ float pbuf[2][4][16][17];        // K-half partial sums

  const int tid = threadIdx.x;
  const int bid = blockIdx.x;
  const int r   = bid & 7;          // rowgroup
  const int cgi = bid >> 3;         // colgroup
  const int rb  = r * 16;
  const int hcb = cgi * 16;

  const int w8    = tid >> 6;       // wave 0..7
  const int gate  = w8 & 3;         // 0=f,1=i,2=o,3=g
  const int khalf = w8 >> 2;        // K-half: 0 -> K 0..383, 1 -> K 384..767
  const int l     = tid & 63;
  const int l16   = l & 15;
  const int lk    = l >> 4;
  const int srow  = tid >> 5;       // staging row 0..15
  const int sn    = tid & 31;       // staging lane 0..31

  unsigned* ring = p.ring;          // valid only in mode 0

  // ---- per-wave B fragments: 12 K-chunks of this wave's K-half ----
  const int col = hcb + l16;
  const float* Wg = p.W[gate];
  const float* Ug = p.U[gate];
  s16x8 bfrag[12];
#pragma unroll
  for (int kk = 0; kk < 12; ++kk) {
    int K = (khalf * 12 + kk) * 32 + lk * 8;
    const float* src = (K < IN_) ? (Wg + (size_t)col * IN_ + K)
                                 : (Ug + (size_t)col * HH + (K - IN_));
    f32x4 a = *(const f32x4*)src;
    f32x4 b = *(const f32x4*)(src + 4);
    s16x8 v;
    v[0]=(short)f2b(a.x); v[1]=(short)f2b(a.y); v[2]=(short)f2b(a.z); v[3]=(short)f2b(a.w);
    v[4]=(short)f2b(b.x); v[5]=(short)f2b(b.y); v[6]=(short)f2b(b.z); v[7]=(short)f2b(b.w);
    bfrag[kk] = v;
  }
  const float bias = (khalf == 0) ? (p.bW[gate][col] + p.bU[gate][col]) : 0.f;

  // cell state: F-phase threads (tid<256) own (row=tid>>4, col=hcb+(tid&15))
  float cval = 0.f;
  if (tid < 256)
    cval = p.c0[(size_t)(rb + (tid >> 4)) * HH + hcb + (tid & 15)];

  const int wswz = (srow & 7) << 4;    // staging-row byte-XOR key
  const int rswz = (l16 & 7) << 4;     // mfma-read byte-XOR key
  char* HsB = (char*)&Hs[0][0];
  char* XsB = (char*)&Xs[0][0][0];

  // ---- prologue: x(t=0) into registers (8 f32/thread) ----
  f32x4 xg0, xg1;
  {
    const float* xs = p.x + (size_t)(rb + srow) * IN_ + sn * 8;
    xg0 = *(const f32x4*)(xs);
    xg1 = *(const f32x4*)(xs + 4);
  }

  for (int t = 0; t < SQ; ++t) {
    // ---- A) Xs[t&1] <- xreg (cvt_pk); issue x(t+1) loads ----
    {
      char* xrow = XsB + (t & 1) * 8192 + srow * 512;
      *(u32x4*)(xrow + ((sn * 16) ^ wswz)) = pack8(xg0, xg1);
      if (t + 1 < SQ) {
        const float* xs = p.x + ((size_t)(t + 1) * BB + rb + srow) * IN_ + sn * 8;
        xg0 = *(const f32x4*)(xs);
        xg1 = *(const f32x4*)(xs + 4);
      }
    }

    // ---- B) obtain h_{t-1} into Hs — tagged LLC ring, 64B/thread ----
    // thread chunk cc: ring dwords (row srow) cols sn*4 + cc*128 + {0..3}
    char* hrow = HsB + srow * 1024;
    if (t == 0) {
      const float* hs = p.h0 + (size_t)(rb + srow) * HH + sn * 4;
#pragma unroll
      for (int cc = 0; cc < 4; ++cc) {
        f32x4 v = *(const f32x4*)(hs + cc * 128);
        uint2 u = make_uint2(cvtpk(v.x, v.y), cvtpk(v.z, v.w));
        *(uint2*)(hrow + ((sn * 8 + cc * 256) ^ wswz)) = u;
      }
    } else if (p.mode == 0) {
      const unsigned* hb = ring + (((t - 1) & 1) ? RINGHALF : 0)
                         + (size_t)(rb + srow) * HH + sn * 4;
      u32x4 c0, c1, c2, c3;
      const unsigned tgw = (unsigned)t << 16;
      int spin = 0;
      for (;;) {
        LOAD4S_LLC(c0, c1, c2, c3, hb);
        unsigned m = (c0.x^tgw)|(c0.y^tgw)|(c0.z^tgw)|(c0.w^tgw)
                   | (c1.x^tgw)|(c1.y^tgw)|(c1.z^tgw)|(c1.w^tgw)
                   | (c2.x^tgw)|(c2.y^tgw)|(c2.z^tgw)|(c2.w^tgw)
                   | (c3.x^tgw)|(c3.y^tgw)|(c3.z^tgw)|(c3.w^tgw);
        if ((m & 0xFFFF0000u) == 0u) break;
        if (++spin > (1 << 16)) break;   // bounded: fail loud, never hang
        if (spin > 8) __builtin_amdgcn_s_sleep(1);
      }
      *(uint2*)(hrow + ((sn * 8)       ^ wswz)) =
          make_uint2(mergelo(c0.x, c0.y), mergelo(c0.z, c0.w));
      *(uint2*)(hrow + ((sn * 8 + 256) ^ wswz)) =
          make_uint2(mergelo(c1.x, c1.y), mergelo(c1.z, c1.w));
      *(uint2*)(hrow + ((sn * 8 + 512) ^ wswz)) =
          make_uint2(mergelo(c2.x, c2.y), mergelo(c2.z, c2.w));
      *(uint2*)(hrow + ((sn * 8 + 768) ^ wswz)) =
          make_uint2(mergelo(c3.x, c3.y), mergelo(c3.z, c3.w));
    } else {
      // gridsync fallback: f32 h from d_out via LLC
      cg::this_grid().sync();
      const float* hp = p.out + ((size_t)(t - 1) * BB + rb + srow) * HH + sn * 4;
      u32x4 a0, a1, a2, a3;
      LOAD4S_LLC(a0, a1, a2, a3, hp);
      f32x4 f0 = __builtin_bit_cast(f32x4, a0);
      f32x4 f1 = __builtin_bit_cast(f32x4, a1);
      f32x4 f2 = __builtin_bit_cast(f32x4, a2);
      f32x4 f3 = __builtin_bit_cast(f32x4, a3);
      *(uint2*)(hrow + ((sn * 8)       ^ wswz)) = make_uint2(cvtpk(f0.x,f0.y), cvtpk(f0.z,f0.w));
      *(uint2*)(hrow + ((sn * 8 + 256) ^ wswz)) = make_uint2(cvtpk(f1.x,f1.y), cvtpk(f1.z,f1.w));
      *(uint2*)(hrow + ((sn * 8 + 512) ^ wswz)) = make_uint2(cvtpk(f2.x,f2.y), cvtpk(f2.z,f2.w));
      *(uint2*)(hrow + ((sn * 8 + 768) ^ wswz)) = make_uint2(cvtpk(f3.x,f3.y), cvtpk(f3.z,f3.w));
    }
    __syncthreads();   // barrier 1: Xs[t&1] + Hs ready

    // ---- D) 12 MFMAs per wave (K-half split), 2 acc chains ----
    f32x4 acc0 = { bias, bias, bias, bias };
    f32x4 acc1 = { 0.f, 0.f, 0.f, 0.f };
    const char* xr = XsB + (t & 1) * 8192 + l16 * 512;
    const char* hr = HsB + l16 * 1024;
#pragma unroll
    for (int kk = 0; kk < 12; kk += 2) {
      int K32a = khalf * 12 + kk;        // compile-time per unrolled iter
      int K32b = K32a + 1;
      const char* pa = (K32a < 8) ? (xr + ((K32a * 64 + lk * 16) ^ rswz))
                                  : (hr + (((K32a - 8) * 64 + lk * 16) ^ rswz));
      const char* pb = (K32b < 8) ? (xr + ((K32b * 64 + lk * 16) ^ rswz))
                                  : (hr + (((K32b - 8) * 64 + lk * 16) ^ rswz));
      s16x8 a0 = *(const s16x8*)pa;
      s16x8 a1 = *(const s16x8*)pb;
      acc0 = __builtin_amdgcn_mfma_f32_16x16x32_bf16(a0, bfrag[kk],     acc0, 0, 0, 0);
      acc1 = __builtin_amdgcn_mfma_f32_16x16x32_bf16(a1, bfrag[kk + 1], acc1, 0, 0, 0);
    }

    // ---- E) partial sums -> pbuf (D-frag: row=lk*4+rr, col=l16) ----
#pragma unroll
    for (int rr = 0; rr < 4; ++rr)
      pbuf[khalf][gate][lk * 4 + rr][l16] = acc0[rr] + acc1[rr];
    __syncthreads();   // barrier 2: pbuf ready

    // ---- F) combine halves, activations, cell update, publish (tid<256) ----
    if (tid < 256) {
      const int fr = tid >> 4;        // row 0..15
      const int fc = tid & 15;        // col 0..15
      float f = sigm (pbuf[0][0][fr][fc] + pbuf[1][0][fr][fc]);
      float i = sigm (pbuf[0][1][fr][fc] + pbuf[1][1][fr][fc]);
      float o = sigm (pbuf[0][2][fr][fc] + pbuf[1][2][fr][fc]);
      float g = tanh_(pbuf[0][3][fr][fc] + pbuf[1][3][fr][fc]);
      cval = f * cval + i * g;
      float h = o * tanh_(cval);

      size_t oidx = ((size_t)t * BB + rb + fr) * HH + hcb + fc;
      if (p.mode == 0) {
        unsigned tw = ((unsigned)(t + 1) << 16) | f2b(h);
        unsigned* dst = ring + ((t & 1) ? RINGHALF : 0)
                      + (size_t)(rb + fr) * HH + hcb + fc;
        asm volatile("global_store_dword %0, %1, off sc0 sc1"
                     :: "v"(dst), "v"(tw) : "memory");
        __builtin_nontemporal_store(h, p.out + oidx);
      } else {
        asm volatile("global_store_dword %0, %1, off sc0 sc1"
                     :: "v"(p.out + oidx), "v"(h) : "memory");
        asm volatile("s_waitcnt vmcnt(0)" ::: "memory");
      }
      if (t == SQ - 1) {
        size_t base = (size_t)SQ * BB * HH;
        size_t idx2 = (size_t)(rb + fr) * HH + hcb + fc;
        p.out[base + idx2] = h;
        p.out[base + (size_t)BB * HH + idx2] = cval;
      }
    }
    // reuse safety: Hs/Xs rewritten next iter only by waves past barrier 2
    // (all MFMA(t) reads done); pbuf rewritten only after next barrier 1
    // (all F(t) reads done). Ring WAR safe via 2-deep ring as in round 8.
  }
}

extern "C" void kernel_launch(void* const* d_in, const int* in_sizes, int n_in,
                              void* d_out, int out_size, void* d_ws, size_t ws_size,
                              hipStream_t stream) {
  P p;
  p.x  = (const float*)d_in[0];
  p.h0 = (const float*)d_in[1];
  p.c0 = (const float*)d_in[2];
  for (int g = 0; g < 4; ++g) {
    p.W[g]  = (const float*)d_in[3 + 4 * g];
    p.bW[g] = (const float*)d_in[4 + 4 * g];
    p.U[g]  = (const float*)d_in[5 + 4 * g];
    p.bU[g] = (const float*)d_in[6 + 4 * g];
  }
  p.out = (float*)d_out;

  const size_t need = (size_t)(RING_OFF + 2 * BB * HH) * sizeof(unsigned);
  const bool ws_ok = (d_ws != nullptr) && (ws_size >= need);
  p.mode = ws_ok ? 0 : 2;
  p.ring = ws_ok ? ((unsigned*)d_ws + RING_OFF) : nullptr;
  if (ws_ok) hipMemsetAsync(d_ws, 0, need, stream);   // tags=0: never valid

  void* args[] = { &p };
  hipError_t e = hipLaunchCooperativeKernel((const void*)lstm_all,
                                            dim3(RG * CGN), dim3(512),
                                            args, 0, stream);
  if (e != hipSuccess) {
    // plain launch: 256 blocks at 1/CU are co-resident; ring protocol valid
    hipLaunchKernelGGL(lstm_all, dim3(RG * CGN), dim3(512), 0, stream, p);
  }
}